// Round 4
// baseline (1906.592 us; speedup 1.0000x reference)
//
#include <hip/hip_runtime.h>

typedef unsigned int u32;

#define N_NODE_ 500
#define N_POD_  20000
#define N_SVC_  2000
#define N_TOT_  22500
#define T_ 16
#define F_ 64
#define H_ 128
#define O_ 64

// ---------------- static device scratch (no d_ws use) ----------------
// float region
#define OF_OUTD_SC  0
#define OF_IND_SC   2000
#define OF_OUTD_IN  4000
#define OF_IND_IN   24000
#define OF_OUTD_NI  24500
#define OF_IND_NI   25000
#define OF_OUTD_II  45000
#define OF_IND_II   65000
#define OF_OUTD_SI  85000
#define OF_IND_SI   87000
#define OF_OUTD_IS  107000
#define OF_IND_IS   127000
#define OF_DEG_END  129000
// LSTM weights, gate-interleaved transposed layout:
//   W[k][j][q] at offset k*256 + j*4 + q, value = W_orig[q*64 + j][k]
// OF_W0: [192][256]  (k<128: Wih0, k>=128: Whh0)
// OF_W1: [128][256]  (k<64:  Wih1, k>=64:  Whh1)
#define OF_W0       129024
#define OF_W1       (129024 + 49152)
#define G_F_SIZE    (129024 + 81920)
// int region (cnt doubles as fill cursor after re-zero)
#define OI_CNT_IN 0
#define OI_CNT_NI 500
#define OI_CNT_II 20500
#define OI_CNT_SI 40500
#define OI_CNT_SC 60500
#define OI_CNT_IS 62500
#define OI_CNT_END 64500
#define OI_OFF_IN 64500
#define OI_OFF_NI 65001
#define OI_OFF_II 85002
#define OI_OFF_SI 105003
#define OI_OFF_SC 125004
#define OI_OFF_IS 127005
#define OI_CSR_IN 129006
#define OI_CSR_NI 149006
#define OI_CSR_II 169006
#define OI_CSR_SI 269006
#define OI_CSR_SC 289006
#define OI_CSR_IS 305006
#define G_I_SIZE  325006

__device__ __align__(16) float g_f[G_F_SIZE];
__device__ int g_i[G_I_SIZE];

__device__ __forceinline__ float sigf(float x) { return 1.0f / (1.0f + __expf(-x)); }

// fast tanh via v_exp: tanh(x) = sign(x) * (1 - 2/(exp(2|x|)+1)); exact at 0, ±1 at inf
__device__ __forceinline__ float tanhf_fast(float x) {
  float ax = fabsf(x);
  float e = __expf(2.0f * ax);
  float t = 1.0f - 2.0f / (e + 1.0f);
  return copysignf(t, x);
}

// ---------- zero the accumulated scratch regions (every launch) ----------
__global__ void zero_k() {
  int i = blockIdx.x * 256 + threadIdx.x;
  if (i < OF_DEG_END + 24) g_f[i] = 0.0f;
  if (i < OI_CNT_END) g_i[i] = 0;
}

// ---------- per-relation metadata (passed by value) ----------
struct Rels {
  const int* src[6];
  const int* dst[6];
  int n[6];
  int o_outd[6];
  int o_ind[6];
  int o_cnt[6];
  int o_off[6];
  int o_csr[6];
};

// all 6 relations in one 2D launch: y = relation
__global__ void deg_all_k(Rels R) {
  int rel = blockIdx.y;
  int e = blockIdx.x * 256 + threadIdx.x;
  if (e < R.n[rel]) {
    atomicAdd(&g_f[R.o_outd[rel] + R.src[rel][e]], 1.0f);
    atomicAdd(&g_f[R.o_ind[rel] + R.dst[rel][e]], 1.0f);
    atomicAdd(&g_i[R.o_cnt[rel] + R.dst[rel][e]], 1);
  }
}

__global__ void fill_all_k(Rels R) {
  int rel = blockIdx.y;
  int e = blockIdx.x * 256 + threadIdx.x;
  if (e < R.n[rel]) {
    int d = R.dst[rel][e];
    int p = atomicAdd(&g_i[R.o_cnt[rel] + d], 1);
    g_i[R.o_csr[rel] + g_i[R.o_off[rel] + d] + p] = R.src[rel][e];
  }
}

// rsqrt of all degrees + all 4 LSTM weight transposes, one launch
__device__ __forceinline__ void tw_one(const float* __restrict__ in, int o_out, int K, int idx) {
  int r = idx / K, k = idx - r * K;
  int q = r >> 6, j = r & 63;
  g_f[o_out + k * 256 + (j << 2) + q] = in[idx];
}

#define PREP2_TOT (OF_DEG_END + 32768 + 16384 + 16384 + 16384)
__global__ void prep2_k(const float* __restrict__ Wih0, const float* __restrict__ Whh0,
                        const float* __restrict__ Wih1, const float* __restrict__ Whh1) {
  int i = blockIdx.x * 256 + threadIdx.x;
  if (i < OF_DEG_END) { g_f[i] = rsqrtf(fmaxf(g_f[i], 1.0f)); return; }
  int j = i - OF_DEG_END;
  if (j < 32768) { tw_one(Wih0, OF_W0, 128, j); return; }
  j -= 32768;
  if (j < 16384) { tw_one(Whh0, OF_W0 + 32768, 64, j); return; }
  j -= 16384;
  if (j < 16384) { tw_one(Wih1, OF_W1, 64, j); return; }
  j -= 16384;
  if (j < 16384) { tw_one(Whh1, OF_W1 + 16384, 64, j); return; }
}

// ---------- 6 single-block exclusive scans (also re-zeroes cnt for fill) ----------
__global__ void exscan6_k() {
  const int cnto[6] = {OI_CNT_IN, OI_CNT_NI, OI_CNT_II, OI_CNT_SI, OI_CNT_SC, OI_CNT_IS};
  const int offo[6] = {OI_OFF_IN, OI_OFF_NI, OI_OFF_II, OI_OFF_SI, OI_OFF_SC, OI_OFF_IS};
  const int ns[6] = {500, 20000, 20000, 20000, 2000, 2000};
  int rel = blockIdx.x;
  int* cnt = g_i + cnto[rel];
  int* off = g_i + offo[rel];
  int n = ns[rel];
  __shared__ int base_s[257];
  __shared__ int part[256];
  int tid = threadIdx.x;
  int chunk = (n + 255) >> 8;
  int lo = tid * chunk;
  int hi = lo + chunk; if (hi > n) hi = n;
  int s = 0;
  for (int i = lo; i < hi; ++i) s += cnt[i];
  part[tid] = s;
  __syncthreads();
  if (tid == 0) {
    int run = 0;
    for (int j = 0; j < 256; ++j) { base_s[j] = run; run += part[j]; }
    base_s[256] = run;
  }
  __syncthreads();
  int run = base_s[tid];
  for (int i = lo; i < hi; ++i) { off[i] = run; run += cnt[i]; cnt[i] = 0; }
  if (tid == 0) off[n] = base_s[256];
}

// ---------- fused gather + GEMM per dst node ----------
// block = one dst node; 256 threads; out[t][h] = relu(scale*(sum_rel m_rel*rsqrt(ind)*W_rel + b_rel))
template <int NREL>
__global__ __launch_bounds__(256) void gconv_gather_k(
    const float* __restrict__ x0, const float* __restrict__ x1, const float* __restrict__ x2,
    int off0, int off1, int off2, int csr0, int csr1, int csr2,
    int od0, int od1, int od2, int id0, int id1, int id2,
    const float* __restrict__ W0, const float* __restrict__ W1, const float* __restrict__ W2,
    const float* __restrict__ b0, const float* __restrict__ b1, const float* __restrict__ b2,
    float scale, float* __restrict__ outp) {
  const float* xs_[3] = {x0, x1, x2};
  const int offs[3] = {off0, off1, off2};
  const int csrs[3] = {csr0, csr1, csr2};
  const int ods[3] = {od0, od1, od2};
  const int ids[3] = {id0, id1, id2};
  const float* Ws[3] = {W0, W1, W2};
  const float* bs[3] = {b0, b1, b2};

  int node = blockIdx.x;
  int tid = threadIdx.x;
  int c = tid & 127;
  int rg = tid >> 7;  // 0/1 -> t rows [0,8) / [8,16)
  __shared__ float msh[T_][F_];  // flat index = t*64+f

  float bb = 0.0f;
#pragma unroll
  for (int rel = 0; rel < NREL; ++rel) bb += bs[rel][c];
  float acc[8];
#pragma unroll
  for (int i = 0; i < 8; ++i) acc[i] = bb;

#pragma unroll
  for (int rel = 0; rel < NREL; ++rel) {
    int e0 = g_i[offs[rel] + node], e1 = g_i[offs[rel] + node + 1];
    const int* csr = g_i + csrs[rel];
    const float* od = g_f + ods[rel];
    const float* xr = xs_[rel];
    // thread owns 4 contiguous elements of the 1024-float [T,F] row
    float a0 = 0.0f, a1 = 0.0f, a2 = 0.0f, a3 = 0.0f;
    for (int e = e0; e < e1; ++e) {
      int s = csr[e];
      float rs = od[s];
      float4 v = ((const float4*)(xr + (size_t)s * 1024))[tid];
      a0 += v.x * rs;
      a1 += v.y * rs;
      a2 += v.z * rs;
      a3 += v.w * rs;
    }
    __syncthreads();  // previous rel's GEMM reads done
    float* mf = &msh[0][0];
    mf[tid * 4 + 0] = a0;
    mf[tid * 4 + 1] = a1;
    mf[tid * 4 + 2] = a2;
    mf[tid * 4 + 3] = a3;
    __syncthreads();
    float rind = g_f[ids[rel] + node];
    const float* W = Ws[rel];
#pragma unroll 4
    for (int f = 0; f < F_; ++f) {
      float w = W[f * H_ + c] * rind;
#pragma unroll
      for (int i = 0; i < 8; ++i) acc[i] += msh[rg * 8 + i][f] * w;
    }
  }
  float* o = outp + (size_t)node * (T_ * H_);
#pragma unroll
  for (int i = 0; i < 8; ++i) {
    float v = acc[i] * scale;
    o[(rg * 8 + i) * H_ + c] = fmaxf(v, 0.0f);
  }
}

// ---------- 2-layer LSTM: LDS-broadcast, wave-private, barrier-free ----------
// Grid: 1024 blocks x 256 threads (4 waves), RW=6 rows/wave (1024*4*6=24576>=22500).
// Exactly 4 blocks/CU -> 4 waves/SIMD (the round-3 version was grid-capped at
// 2 waves/SIMD with VALUBusy 70%: a 30% latency bubble; this doubles TLP).
// Lane l owns hidden unit l (all 4 gates). Broadcast operands in wave-private
// LDS slice xh[r][256] = [x_t | h0 | h1]; uniform-address ds_read_b128.
// x for t+1 is prefetched into registers during t's compute (global-load
// latency hides under the gemv). No __syncthreads anywhere.
#define RW 6

__device__ __forceinline__ void gemv_lds(float acc[RW][4], const float* xrow0,
                                         const float4* __restrict__ Wb, int nk4, int l) {
#pragma unroll 2
  for (int k4 = 0; k4 < nk4; ++k4) {
    const float4* wp = Wb + (k4 << 8) + l;  // 4 consecutive k rows of [64]float4
    float4 w0 = wp[0];
    float4 w1 = wp[64];
    float4 w2 = wp[128];
    float4 w3 = wp[192];
#pragma unroll
    for (int r = 0; r < RW; ++r) {
      float4 xv = *(const float4*)(xrow0 + r * 256 + k4 * 4);  // ds_read_b128, uniform addr
      acc[r][0] += xv.x * w0.x; acc[r][1] += xv.x * w0.y; acc[r][2] += xv.x * w0.z; acc[r][3] += xv.x * w0.w;
      acc[r][0] += xv.y * w1.x; acc[r][1] += xv.y * w1.y; acc[r][2] += xv.y * w1.z; acc[r][3] += xv.y * w1.w;
      acc[r][0] += xv.z * w2.x; acc[r][1] += xv.z * w2.y; acc[r][2] += xv.z * w2.z; acc[r][3] += xv.z * w2.w;
      acc[r][0] += xv.w * w3.x; acc[r][1] += xv.w * w3.y; acc[r][2] += xv.w * w3.z; acc[r][3] += xv.w * w3.w;
    }
  }
}

__global__ __launch_bounds__(256, 4) void lstm_lds_k(
    const float* __restrict__ feat,  // [N_TOT,16,128] fp32 (post-relu)
    const float* __restrict__ bih0, const float* __restrict__ bhh0,
    const float* __restrict__ bih1, const float* __restrict__ bhh1,
    float* __restrict__ out2) {
  const float4* W0v = (const float4*)(g_f + OF_W0);  // [192][64] float4
  const float4* W1v = (const float4*)(g_f + OF_W1);  // [128][64] float4
  __shared__ __align__(16) float xh[4][RW][256];     // 24576 B
  int tid = threadIdx.x;
  int l = tid & 63;
  int wid = tid >> 6;
  int row0 = (blockIdx.x * 4 + wid) * RW;
  float* xw = &xh[wid][0][0];

  float bb0[4], bb1[4];
#pragma unroll
  for (int q = 0; q < 4; ++q) {
    bb0[q] = bih0[q * 64 + l] + bhh0[q * 64 + l];
    bb1[q] = bih1[q * 64 + l] + bhh1[q * 64 + l];
  }

  const float* xb[RW];
  bool vld[RW];
#pragma unroll
  for (int r = 0; r < RW; ++r) {
    int row = row0 + r;
    vld[r] = row < N_TOT_;
    xb[r] = feat + (size_t)(vld[r] ? row : 0) * (T_ * H_);
  }

  float c0[RW] = {}, c1[RW] = {};
  // zero h0/h1 regions (wave-private, no barrier needed)
#pragma unroll
  for (int r = 0; r < RW; ++r) {
    xw[r * 256 + 128 + l] = 0.0f;
    xw[r * 256 + 192 + l] = 0.0f;
  }

  // preload x for t=0
  float xn0[RW], xn1[RW];
#pragma unroll
  for (int r = 0; r < RW; ++r) {
    xn0[r] = xb[r][l];
    xn1[r] = xb[r][64 + l];
  }

  for (int t = 0; t < T_; ++t) {
    // stage x_t from registers into the wave's LDS slice
#pragma unroll
    for (int r = 0; r < RW; ++r) {
      xw[r * 256 + l] = xn0[r];
      xw[r * 256 + 64 + l] = xn1[r];
    }
    // prefetch x_{t+1} (consumed at next iteration's staging; latency hides
    // under both gemvs). t=15 harmlessly re-reads t=0.
    int tn = (t + 1) & 15;
#pragma unroll
    for (int r = 0; r < RW; ++r) {
      xn0[r] = xb[r][tn * H_ + l];
      xn1[r] = xb[r][tn * H_ + 64 + l];
    }

    float acc[RW][4];
#pragma unroll
    for (int r = 0; r < RW; ++r)
#pragma unroll
      for (int q = 0; q < 4; ++q) acc[r][q] = bb0[q];

    // layer 0: [x_t | h0_prev] @ [Wih0 | Whh0], K=192 contiguous in LDS
    gemv_lds(acc, xw, W0v, 48, l);

#pragma unroll
    for (int r = 0; r < RW; ++r) {
      float iv = sigf(acc[r][0]);
      float fv = sigf(acc[r][1]);
      float gv = tanhf_fast(acc[r][2]);
      float ov = sigf(acc[r][3]);
      float cc = fv * c0[r] + iv * gv;
      c0[r] = cc;
      xw[r * 256 + 128 + l] = ov * tanhf_fast(cc);  // h0_new -> LDS
    }

#pragma unroll
    for (int r = 0; r < RW; ++r)
#pragma unroll
      for (int q = 0; q < 4; ++q) acc[r][q] = bb1[q];

    // layer 1: [h0_new | h1_prev] @ [Wih1 | Whh1], K=128 contiguous in LDS
    gemv_lds(acc, xw + 128, W1v, 32, l);

#pragma unroll
    for (int r = 0; r < RW; ++r) {
      float iv = sigf(acc[r][0]);
      float fv = sigf(acc[r][1]);
      float gv = tanhf_fast(acc[r][2]);
      float ov = sigf(acc[r][3]);
      float cc = fv * c1[r] + iv * gv;
      c1[r] = cc;
      float hh = ov * tanhf_fast(cc);
      xw[r * 256 + 192 + l] = hh;  // h1_new -> LDS
      if (vld[r]) out2[((size_t)(row0 + r) * T_ + t) * O_ + l] = fmaxf(hh, 0.0f);
    }
  }
}

extern "C" void kernel_launch(void* const* d_in, const int* in_sizes, int n_in,
                              void* d_out, int out_size, void* d_ws, size_t ws_size,
                              hipStream_t stream) {
  (void)in_sizes; (void)n_in; (void)out_size; (void)d_ws; (void)ws_size;
  const float* x_node = (const float*)d_in[0];
  const float* x_pod  = (const float*)d_in[1];
  const float* x_svc  = (const float*)d_in[2];
  const int* sc_src = (const int*)d_in[3];
  const int* sc_dst = (const int*)d_in[4];
  const int* in_src = (const int*)d_in[5];
  const int* in_dst = (const int*)d_in[6];
  const int* ni_src = (const int*)d_in[7];
  const int* ni_dst = (const int*)d_in[8];
  const int* ii_src = (const int*)d_in[9];
  const int* ii_dst = (const int*)d_in[10];
  const int* si_src = (const int*)d_in[11];
  const int* si_dst = (const int*)d_in[12];
  const int* is_src = (const int*)d_in[13];
  const int* is_dst = (const int*)d_in[14];
  const float* W_sc = (const float*)d_in[15]; const float* b_sc = (const float*)d_in[16];
  const float* W_in = (const float*)d_in[17]; const float* b_in = (const float*)d_in[18];
  const float* W_ni = (const float*)d_in[19]; const float* b_ni = (const float*)d_in[20];
  const float* W_ii = (const float*)d_in[21]; const float* b_ii = (const float*)d_in[22];
  const float* W_si = (const float*)d_in[23]; const float* b_si = (const float*)d_in[24];
  const float* W_is = (const float*)d_in[25]; const float* b_is = (const float*)d_in[26];
  const float* Wih0 = (const float*)d_in[27]; const float* Whh0 = (const float*)d_in[28];
  const float* bih0 = (const float*)d_in[29]; const float* bhh0 = (const float*)d_in[30];
  const float* Wih1 = (const float*)d_in[31]; const float* Whh1 = (const float*)d_in[32];
  const float* bih1 = (const float*)d_in[33]; const float* bhh1 = (const float*)d_in[34];

  float* out_feat = (float*)d_out;
  float* out_h = out_feat + (size_t)N_TOT_ * T_ * H_;  // +46,080,000

  Rels R;
  R.src[0] = in_src; R.dst[0] = in_dst; R.n[0] = 20000;
  R.o_outd[0] = OF_OUTD_IN; R.o_ind[0] = OF_IND_IN; R.o_cnt[0] = OI_CNT_IN;
  R.o_off[0] = OI_OFF_IN; R.o_csr[0] = OI_CSR_IN;
  R.src[1] = ni_src; R.dst[1] = ni_dst; R.n[1] = 20000;
  R.o_outd[1] = OF_OUTD_NI; R.o_ind[1] = OF_IND_NI; R.o_cnt[1] = OI_CNT_NI;
  R.o_off[1] = OI_OFF_NI; R.o_csr[1] = OI_CSR_NI;
  R.src[2] = ii_src; R.dst[2] = ii_dst; R.n[2] = 100000;
  R.o_outd[2] = OF_OUTD_II; R.o_ind[2] = OF_IND_II; R.o_cnt[2] = OI_CNT_II;
  R.o_off[2] = OI_OFF_II; R.o_csr[2] = OI_CSR_II;
  R.src[3] = si_src; R.dst[3] = si_dst; R.n[3] = 20000;
  R.o_outd[3] = OF_OUTD_SI; R.o_ind[3] = OF_IND_SI; R.o_cnt[3] = OI_CNT_SI;
  R.o_off[3] = OI_OFF_SI; R.o_csr[3] = OI_CSR_SI;
  R.src[4] = sc_src; R.dst[4] = sc_dst; R.n[4] = 16000;
  R.o_outd[4] = OF_OUTD_SC; R.o_ind[4] = OF_IND_SC; R.o_cnt[4] = OI_CNT_SC;
  R.o_off[4] = OI_OFF_SC; R.o_csr[4] = OI_CSR_SC;
  R.src[5] = is_src; R.dst[5] = is_dst; R.n[5] = 20000;
  R.o_outd[5] = OF_OUTD_IS; R.o_ind[5] = OF_IND_IS; R.o_cnt[5] = OI_CNT_IS;
  R.o_off[5] = OI_OFF_IS; R.o_csr[5] = OI_CSR_IS;

  // zero accumulated scratch
  zero_k<<<(OF_DEG_END + 24 + 255) / 256, 256, 0, stream>>>();

  // degrees + counts, all relations (2D grid; small rels exit early)
  deg_all_k<<<dim3((100000 + 255) / 256, 6), 256, 0, stream>>>(R);

  // rsqrt degrees + all 4 LSTM weight transposes
  prep2_k<<<(PREP2_TOT + 255) / 256, 256, 0, stream>>>(Wih0, Whh0, Wih1, Whh1);

  // CSR build (exscan also re-zeroes cnt for use as fill cursor)
  exscan6_k<<<6, 256, 0, stream>>>();
  fill_all_k<<<dim3((100000 + 255) / 256, 6), 256, 0, stream>>>(R);

  // fused gather + GEMM per dst type
  gconv_gather_k<1><<<N_NODE_, 256, 0, stream>>>(
      x_pod, nullptr, nullptr, OI_OFF_IN, 0, 0, OI_CSR_IN, 0, 0,
      OF_OUTD_IN, 0, 0, OF_IND_IN, 0, 0,
      W_in, nullptr, nullptr, b_in, nullptr, nullptr, 1.0f, out_feat);
  gconv_gather_k<3><<<N_POD_, 256, 0, stream>>>(
      x_node, x_pod, x_svc, OI_OFF_NI, OI_OFF_II, OI_OFF_SI, OI_CSR_NI, OI_CSR_II, OI_CSR_SI,
      OF_OUTD_NI, OF_OUTD_II, OF_OUTD_SI, OF_IND_NI, OF_IND_II, OF_IND_SI,
      W_ni, W_ii, W_si, b_ni, b_ii, b_si, 1.0f / 3.0f,
      out_feat + (size_t)N_NODE_ * (T_ * H_));
  gconv_gather_k<2><<<N_SVC_, 256, 0, stream>>>(
      x_svc, x_pod, nullptr, OI_OFF_SC, OI_OFF_IS, 0, OI_CSR_SC, OI_CSR_IS, 0,
      OF_OUTD_SC, OF_OUTD_IS, 0, OF_IND_SC, OF_IND_IS, 0,
      W_sc, W_is, nullptr, b_sc, b_is, nullptr, 0.5f,
      out_feat + (size_t)(N_NODE_ + N_POD_) * (T_ * H_));

  // 2-layer LSTM: LDS-broadcast, 4 blocks/CU, x-prefetch, barrier-free
  lstm_lds_k<<<1024, 256, 0, stream>>>(
      out_feat, bih0, bhh0, bih1, bhh1, out_h);
}

// Round 5
// 1756.267 us; speedup vs baseline: 1.0856x; 1.0856x over previous
//
#include <hip/hip_runtime.h>

typedef unsigned int u32;

#define N_NODE_ 500
#define N_POD_  20000
#define N_SVC_  2000
#define N_TOT_  22500
#define T_ 16
#define F_ 64
#define H_ 128
#define O_ 64

// ---------------- static device scratch (no d_ws use) ----------------
// float region
#define OF_OUTD_SC  0
#define OF_IND_SC   2000
#define OF_OUTD_IN  4000
#define OF_IND_IN   24000
#define OF_OUTD_NI  24500
#define OF_IND_NI   25000
#define OF_OUTD_II  45000
#define OF_IND_II   65000
#define OF_OUTD_SI  85000
#define OF_IND_SI   87000
#define OF_OUTD_IS  107000
#define OF_IND_IS   127000
#define OF_DEG_END  129000
// LSTM weights, gate-interleaved transposed layout:
//   W[k][j][q] at offset k*256 + j*4 + q, value = W_orig[q*64 + j][k]
// OF_W0: [192][256]  (k<128: Wih0, k>=128: Whh0)
// OF_W1: [128][256]  (k<64:  Wih1, k>=64:  Whh1)  -- contiguous after W0,
// so [320][256] = [320][64] float4 total: the LSTM streams it as one array.
#define OF_W0       129024
#define OF_W1       (129024 + 49152)
#define G_F_SIZE    (129024 + 81920)
// int region (cnt doubles as fill cursor after re-zero)
#define OI_CNT_IN 0
#define OI_CNT_NI 500
#define OI_CNT_II 20500
#define OI_CNT_SI 40500
#define OI_CNT_SC 60500
#define OI_CNT_IS 62500
#define OI_CNT_END 64500
#define OI_OFF_IN 64500
#define OI_OFF_NI 65001
#define OI_OFF_II 85002
#define OI_OFF_SI 105003
#define OI_OFF_SC 125004
#define OI_OFF_IS 127005
#define OI_CSR_IN 129006
#define OI_CSR_NI 149006
#define OI_CSR_II 169006
#define OI_CSR_SI 269006
#define OI_CSR_SC 289006
#define OI_CSR_IS 305006
#define G_I_SIZE  325006

__device__ __align__(16) float g_f[G_F_SIZE];
__device__ int g_i[G_I_SIZE];

__device__ __forceinline__ float sigf(float x) { return 1.0f / (1.0f + __expf(-x)); }

// fast tanh via v_exp: tanh(x) = sign(x) * (1 - 2/(exp(2|x|)+1)); exact at 0, ±1 at inf
__device__ __forceinline__ float tanhf_fast(float x) {
  float ax = fabsf(x);
  float e = __expf(2.0f * ax);
  float t = 1.0f - 2.0f / (e + 1.0f);
  return copysignf(t, x);
}

// ---------- zero the accumulated scratch regions (every launch) ----------
__global__ void zero_k() {
  int i = blockIdx.x * 256 + threadIdx.x;
  if (i < OF_DEG_END + 24) g_f[i] = 0.0f;
  if (i < OI_CNT_END) g_i[i] = 0;
}

// ---------- per-relation metadata (passed by value) ----------
struct Rels {
  const int* src[6];
  const int* dst[6];
  int n[6];
  int o_outd[6];
  int o_ind[6];
  int o_cnt[6];
  int o_off[6];
  int o_csr[6];
};

// all 6 relations in one 2D launch: y = relation
__global__ void deg_all_k(Rels R) {
  int rel = blockIdx.y;
  int e = blockIdx.x * 256 + threadIdx.x;
  if (e < R.n[rel]) {
    atomicAdd(&g_f[R.o_outd[rel] + R.src[rel][e]], 1.0f);
    atomicAdd(&g_f[R.o_ind[rel] + R.dst[rel][e]], 1.0f);
    atomicAdd(&g_i[R.o_cnt[rel] + R.dst[rel][e]], 1);
  }
}

__global__ void fill_all_k(Rels R) {
  int rel = blockIdx.y;
  int e = blockIdx.x * 256 + threadIdx.x;
  if (e < R.n[rel]) {
    int d = R.dst[rel][e];
    int p = atomicAdd(&g_i[R.o_cnt[rel] + d], 1);
    g_i[R.o_csr[rel] + g_i[R.o_off[rel] + d] + p] = R.src[rel][e];
  }
}

// rsqrt of all degrees + all 4 LSTM weight transposes, one launch
__device__ __forceinline__ void tw_one(const float* __restrict__ in, int o_out, int K, int idx) {
  int r = idx / K, k = idx - r * K;
  int q = r >> 6, j = r & 63;
  g_f[o_out + k * 256 + (j << 2) + q] = in[idx];
}

#define PREP2_TOT (OF_DEG_END + 32768 + 16384 + 16384 + 16384)
__global__ void prep2_k(const float* __restrict__ Wih0, const float* __restrict__ Whh0,
                        const float* __restrict__ Wih1, const float* __restrict__ Whh1) {
  int i = blockIdx.x * 256 + threadIdx.x;
  if (i < OF_DEG_END) { g_f[i] = rsqrtf(fmaxf(g_f[i], 1.0f)); return; }
  int j = i - OF_DEG_END;
  if (j < 32768) { tw_one(Wih0, OF_W0, 128, j); return; }
  j -= 32768;
  if (j < 16384) { tw_one(Whh0, OF_W0 + 32768, 64, j); return; }
  j -= 16384;
  if (j < 16384) { tw_one(Wih1, OF_W1, 64, j); return; }
  j -= 16384;
  if (j < 16384) { tw_one(Whh1, OF_W1 + 16384, 64, j); return; }
}

// ---------- 6 single-block exclusive scans (also re-zeroes cnt for fill) ----------
__global__ void exscan6_k() {
  const int cnto[6] = {OI_CNT_IN, OI_CNT_NI, OI_CNT_II, OI_CNT_SI, OI_CNT_SC, OI_CNT_IS};
  const int offo[6] = {OI_OFF_IN, OI_OFF_NI, OI_OFF_II, OI_OFF_SI, OI_OFF_SC, OI_OFF_IS};
  const int ns[6] = {500, 20000, 20000, 20000, 2000, 2000};
  int rel = blockIdx.x;
  int* cnt = g_i + cnto[rel];
  int* off = g_i + offo[rel];
  int n = ns[rel];
  __shared__ int base_s[257];
  __shared__ int part[256];
  int tid = threadIdx.x;
  int chunk = (n + 255) >> 8;
  int lo = tid * chunk;
  int hi = lo + chunk; if (hi > n) hi = n;
  int s = 0;
  for (int i = lo; i < hi; ++i) s += cnt[i];
  part[tid] = s;
  __syncthreads();
  if (tid == 0) {
    int run = 0;
    for (int j = 0; j < 256; ++j) { base_s[j] = run; run += part[j]; }
    base_s[256] = run;
  }
  __syncthreads();
  int run = base_s[tid];
  for (int i = lo; i < hi; ++i) { off[i] = run; run += cnt[i]; cnt[i] = 0; }
  if (tid == 0) off[n] = base_s[256];
}

// ---------- fused gather + GEMM per dst node ----------
// block = one dst node; 256 threads; out[t][h] = relu(scale*(sum_rel m_rel*rsqrt(ind)*W_rel + b_rel))
template <int NREL>
__global__ __launch_bounds__(256) void gconv_gather_k(
    const float* __restrict__ x0, const float* __restrict__ x1, const float* __restrict__ x2,
    int off0, int off1, int off2, int csr0, int csr1, int csr2,
    int od0, int od1, int od2, int id0, int id1, int id2,
    const float* __restrict__ W0, const float* __restrict__ W1, const float* __restrict__ W2,
    const float* __restrict__ b0, const float* __restrict__ b1, const float* __restrict__ b2,
    float scale, float* __restrict__ outp) {
  const float* xs_[3] = {x0, x1, x2};
  const int offs[3] = {off0, off1, off2};
  const int csrs[3] = {csr0, csr1, csr2};
  const int ods[3] = {od0, od1, od2};
  const int ids[3] = {id0, id1, id2};
  const float* Ws[3] = {W0, W1, W2};
  const float* bs[3] = {b0, b1, b2};

  int node = blockIdx.x;
  int tid = threadIdx.x;
  int c = tid & 127;
  int rg = tid >> 7;  // 0/1 -> t rows [0,8) / [8,16)
  __shared__ float msh[T_][F_];  // flat index = t*64+f

  float bb = 0.0f;
#pragma unroll
  for (int rel = 0; rel < NREL; ++rel) bb += bs[rel][c];
  float acc[8];
#pragma unroll
  for (int i = 0; i < 8; ++i) acc[i] = bb;

#pragma unroll
  for (int rel = 0; rel < NREL; ++rel) {
    int e0 = g_i[offs[rel] + node], e1 = g_i[offs[rel] + node + 1];
    const int* csr = g_i + csrs[rel];
    const float* od = g_f + ods[rel];
    const float* xr = xs_[rel];
    // thread owns 4 contiguous elements of the 1024-float [T,F] row
    float a0 = 0.0f, a1 = 0.0f, a2 = 0.0f, a3 = 0.0f;
    for (int e = e0; e < e1; ++e) {
      int s = csr[e];
      float rs = od[s];
      float4 v = ((const float4*)(xr + (size_t)s * 1024))[tid];
      a0 += v.x * rs;
      a1 += v.y * rs;
      a2 += v.z * rs;
      a3 += v.w * rs;
    }
    __syncthreads();  // previous rel's GEMM reads done
    float* mf = &msh[0][0];
    mf[tid * 4 + 0] = a0;
    mf[tid * 4 + 1] = a1;
    mf[tid * 4 + 2] = a2;
    mf[tid * 4 + 3] = a3;
    __syncthreads();
    float rind = g_f[ids[rel] + node];
    const float* W = Ws[rel];
#pragma unroll 4
    for (int f = 0; f < F_; ++f) {
      float w = W[f * H_ + c] * rind;
#pragma unroll
      for (int i = 0; i < 8; ++i) acc[i] += msh[rg * 8 + i][f] * w;
    }
  }
  float* o = outp + (size_t)node * (T_ * H_);
#pragma unroll
  for (int i = 0; i < 8; ++i) {
    float v = acc[i] * scale;
    o[(rg * 8 + i) * H_ + c] = fmaxf(v, 0.0f);
  }
}

// ---------- 2-layer LSTM: block-shared W stream through LDS ----------
// Geometry = the verified round-3 shape: 512 blocks x 4 waves x RW=11 rows
// (22528 rows, 2 blocks/CU, 2 waves/SIMD). Round-4 lesson: W L2 traffic
// scales with wave count (each wave re-reads 327KB per t), so more waves
// REGRESSES. This version amortizes one W stream across the whole block
// (rows per W-fetch 11 -> 44, W L2 traffic 10.7GB -> 2.7GB) by staging W
// in 8KB chunks (8 k-rows) through a double-buffered LDS region:
//   issue chunk c+1 global loads -> consume chunk c from LDS ->
//   __syncthreads -> ds_write staged regs -> __syncthreads.
// Plain __syncthreads everywhere (its vmcnt drain lands ~1 chunk-consume
// after issue, covering L2 latency) - no manual waitcnt, no races.
// 40 chunks/t (24 = layer0 K=192, 16 = layer1 K=128) cycle continuously
// across t. Broadcast operands (x_t|h0|h1) stay in wave-private LDS slices
// read via uniform-address ds_read_b128, as in round 3.
#define RW 11
#define NCHT 640  // 40 chunks/t * 16 t

__device__ __forceinline__ void consume8(float acc[RW][4], const float4* __restrict__ wb,
                                         const float* xbase, int kbase, int l) {
#pragma unroll
  for (int kk = 0; kk < 2; ++kk) {
    float4 w0 = wb[(kk * 4 + 0) * 64 + l];
    float4 w1 = wb[(kk * 4 + 1) * 64 + l];
    float4 w2 = wb[(kk * 4 + 2) * 64 + l];
    float4 w3 = wb[(kk * 4 + 3) * 64 + l];
    const float* xrp = xbase + kbase + kk * 4;
#pragma unroll
    for (int r = 0; r < RW; ++r) {
      float4 xv = *(const float4*)(xrp + r * 256);  // uniform-addr ds_read_b128
      acc[r][0] += xv.x * w0.x; acc[r][1] += xv.x * w0.y; acc[r][2] += xv.x * w0.z; acc[r][3] += xv.x * w0.w;
      acc[r][0] += xv.y * w1.x; acc[r][1] += xv.y * w1.y; acc[r][2] += xv.y * w1.z; acc[r][3] += xv.y * w1.w;
      acc[r][0] += xv.z * w2.x; acc[r][1] += xv.z * w2.y; acc[r][2] += xv.z * w2.z; acc[r][3] += xv.z * w2.w;
      acc[r][0] += xv.w * w3.x; acc[r][1] += xv.w * w3.y; acc[r][2] += xv.w * w3.z; acc[r][3] += xv.w * w3.w;
    }
  }
}

__global__ __launch_bounds__(256, 2) void lstm_wlds_k(
    const float* __restrict__ feat,  // [N_TOT,16,128] fp32 (post-relu)
    const float* __restrict__ bih0, const float* __restrict__ bhh0,
    const float* __restrict__ bih1, const float* __restrict__ bhh1,
    float* __restrict__ out2) {
  const float4* Wg = (const float4*)(g_f + OF_W0);  // [320][64] float4 (W0|W1)
  __shared__ __align__(16) float xh[4][RW][256];    // 45056 B broadcast slices
  __shared__ float4 wbuf[2][512];                   // 2 x 8KB W chunks
  int tid = threadIdx.x;
  int l = tid & 63;
  int wid = tid >> 6;
  int row0 = (blockIdx.x * 4 + wid) * RW;
  float* xw = &xh[wid][0][0];

  float bb0[4], bb1[4];
#pragma unroll
  for (int q = 0; q < 4; ++q) {
    bb0[q] = bih0[q * 64 + l] + bhh0[q * 64 + l];
    bb1[q] = bih1[q * 64 + l] + bhh1[q * 64 + l];
  }

  const float* xb[RW];
  bool vld[RW];
#pragma unroll
  for (int r = 0; r < RW; ++r) {
    int row = row0 + r;
    vld[r] = row < N_TOT_;
    xb[r] = feat + (size_t)(vld[r] ? row : 0) * (T_ * H_);
  }

  float c0[RW] = {}, c1[RW] = {};
  // zero h0/h1 regions (wave-private)
#pragma unroll
  for (int r = 0; r < RW; ++r) {
    xw[r * 256 + 128 + l] = 0.0f;
    xw[r * 256 + 192 + l] = 0.0f;
  }

  // preload x for t=0
  float xn0[RW], xn1[RW];
#pragma unroll
  for (int r = 0; r < RW; ++r) {
    xn0[r] = xb[r][l];
    xn1[r] = xb[r][64 + l];
  }

  // prologue: fill W chunk 0 into buf0
  {
    float4 s0 = Wg[tid], s1 = Wg[256 + tid];
    wbuf[0][tid] = s0;
    wbuf[0][tid + 256] = s1;
  }
  __syncthreads();

  int gch = 0;  // global chunk counter (0..639)

  auto chunk_step = [&](float (&acc)[RW][4], const float* xbase, int kbase) {
    bool dn = (gch + 1 < NCHT);
    int noff = ((gch + 1) % 40) << 9;
    float4 st0, st1;
    if (dn) {
      st0 = Wg[noff + tid];
      st1 = Wg[noff + 256 + tid];
    }
    consume8(acc, wbuf[gch & 1], xbase, kbase, l);
    __syncthreads();  // all waves done with chunk gch (and buf[gch+1&1] free)
    if (dn) {
      float4* wn = wbuf[(gch + 1) & 1];
      wn[tid] = st0;       // compiler-inserted vmcnt wait covers L2 latency
      wn[tid + 256] = st1;
    }
    __syncthreads();  // chunk gch+1 visible to all
    ++gch;
  };

  for (int t = 0; t < T_; ++t) {
    // stage x_t from prefetch regs into the wave's LDS slice
#pragma unroll
    for (int r = 0; r < RW; ++r) {
      xw[r * 256 + l] = xn0[r];
      xw[r * 256 + 64 + l] = xn1[r];
    }
    // prefetch x_{t+1} (drained harmlessly at the next chunk barrier)
    int tn = (t + 1) & 15;
#pragma unroll
    for (int r = 0; r < RW; ++r) {
      xn0[r] = xb[r][tn * H_ + l];
      xn1[r] = xb[r][tn * H_ + 64 + l];
    }

    float acc[RW][4];
#pragma unroll
    for (int r = 0; r < RW; ++r)
#pragma unroll
      for (int q = 0; q < 4; ++q) acc[r][q] = bb0[q];

    // layer 0: [x_t | h0_prev] @ [Wih0 | Whh0], K=192 = chunks 0..23
    for (int cc = 0; cc < 24; ++cc) chunk_step(acc, xw, cc * 8);

#pragma unroll
    for (int r = 0; r < RW; ++r) {
      float iv = sigf(acc[r][0]);
      float fv = sigf(acc[r][1]);
      float gv = tanhf_fast(acc[r][2]);
      float ov = sigf(acc[r][3]);
      float cc_ = fv * c0[r] + iv * gv;
      c0[r] = cc_;
      xw[r * 256 + 128 + l] = ov * tanhf_fast(cc_);  // h0_new -> LDS
    }

#pragma unroll
    for (int r = 0; r < RW; ++r)
#pragma unroll
      for (int q = 0; q < 4; ++q) acc[r][q] = bb1[q];

    // layer 1: [h0_new | h1_prev] @ [Wih1 | Whh1], K=128 = chunks 24..39
    for (int cc = 0; cc < 16; ++cc) chunk_step(acc, xw + 128, cc * 8);

#pragma unroll
    for (int r = 0; r < RW; ++r) {
      float iv = sigf(acc[r][0]);
      float fv = sigf(acc[r][1]);
      float gv = tanhf_fast(acc[r][2]);
      float ov = sigf(acc[r][3]);
      float cc_ = fv * c1[r] + iv * gv;
      c1[r] = cc_;
      float hh = ov * tanhf_fast(cc_);
      xw[r * 256 + 192 + l] = hh;  // h1_new -> LDS
      if (vld[r]) out2[((size_t)(row0 + r) * T_ + t) * O_ + l] = fmaxf(hh, 0.0f);
    }
  }
}

extern "C" void kernel_launch(void* const* d_in, const int* in_sizes, int n_in,
                              void* d_out, int out_size, void* d_ws, size_t ws_size,
                              hipStream_t stream) {
  (void)in_sizes; (void)n_in; (void)out_size; (void)d_ws; (void)ws_size;
  const float* x_node = (const float*)d_in[0];
  const float* x_pod  = (const float*)d_in[1];
  const float* x_svc  = (const float*)d_in[2];
  const int* sc_src = (const int*)d_in[3];
  const int* sc_dst = (const int*)d_in[4];
  const int* in_src = (const int*)d_in[5];
  const int* in_dst = (const int*)d_in[6];
  const int* ni_src = (const int*)d_in[7];
  const int* ni_dst = (const int*)d_in[8];
  const int* ii_src = (const int*)d_in[9];
  const int* ii_dst = (const int*)d_in[10];
  const int* si_src = (const int*)d_in[11];
  const int* si_dst = (const int*)d_in[12];
  const int* is_src = (const int*)d_in[13];
  const int* is_dst = (const int*)d_in[14];
  const float* W_sc = (const float*)d_in[15]; const float* b_sc = (const float*)d_in[16];
  const float* W_in = (const float*)d_in[17]; const float* b_in = (const float*)d_in[18];
  const float* W_ni = (const float*)d_in[19]; const float* b_ni = (const float*)d_in[20];
  const float* W_ii = (const float*)d_in[21]; const float* b_ii = (const float*)d_in[22];
  const float* W_si = (const float*)d_in[23]; const float* b_si = (const float*)d_in[24];
  const float* W_is = (const float*)d_in[25]; const float* b_is = (const float*)d_in[26];
  const float* Wih0 = (const float*)d_in[27]; const float* Whh0 = (const float*)d_in[28];
  const float* bih0 = (const float*)d_in[29]; const float* bhh0 = (const float*)d_in[30];
  const float* Wih1 = (const float*)d_in[31]; const float* Whh1 = (const float*)d_in[32];
  const float* bih1 = (const float*)d_in[33]; const float* bhh1 = (const float*)d_in[34];

  float* out_feat = (float*)d_out;
  float* out_h = out_feat + (size_t)N_TOT_ * T_ * H_;  // +46,080,000

  Rels R;
  R.src[0] = in_src; R.dst[0] = in_dst; R.n[0] = 20000;
  R.o_outd[0] = OF_OUTD_IN; R.o_ind[0] = OF_IND_IN; R.o_cnt[0] = OI_CNT_IN;
  R.o_off[0] = OI_OFF_IN; R.o_csr[0] = OI_CSR_IN;
  R.src[1] = ni_src; R.dst[1] = ni_dst; R.n[1] = 20000;
  R.o_outd[1] = OF_OUTD_NI; R.o_ind[1] = OF_IND_NI; R.o_cnt[1] = OI_CNT_NI;
  R.o_off[1] = OI_OFF_NI; R.o_csr[1] = OI_CSR_NI;
  R.src[2] = ii_src; R.dst[2] = ii_dst; R.n[2] = 100000;
  R.o_outd[2] = OF_OUTD_II; R.o_ind[2] = OF_IND_II; R.o_cnt[2] = OI_CNT_II;
  R.o_off[2] = OI_OFF_II; R.o_csr[2] = OI_CSR_II;
  R.src[3] = si_src; R.dst[3] = si_dst; R.n[3] = 20000;
  R.o_outd[3] = OF_OUTD_SI; R.o_ind[3] = OF_IND_SI; R.o_cnt[3] = OI_CNT_SI;
  R.o_off[3] = OI_OFF_SI; R.o_csr[3] = OI_CSR_SI;
  R.src[4] = sc_src; R.dst[4] = sc_dst; R.n[4] = 16000;
  R.o_outd[4] = OF_OUTD_SC; R.o_ind[4] = OF_IND_SC; R.o_cnt[4] = OI_CNT_SC;
  R.o_off[4] = OI_OFF_SC; R.o_csr[4] = OI_CSR_SC;
  R.src[5] = is_src; R.dst[5] = is_dst; R.n[5] = 20000;
  R.o_outd[5] = OF_OUTD_IS; R.o_ind[5] = OF_IND_IS; R.o_cnt[5] = OI_CNT_IS;
  R.o_off[5] = OI_OFF_IS; R.o_csr[5] = OI_CSR_IS;

  // zero accumulated scratch
  zero_k<<<(OF_DEG_END + 24 + 255) / 256, 256, 0, stream>>>();

  // degrees + counts, all relations (2D grid; small rels exit early)
  deg_all_k<<<dim3((100000 + 255) / 256, 6), 256, 0, stream>>>(R);

  // rsqrt degrees + all 4 LSTM weight transposes
  prep2_k<<<(PREP2_TOT + 255) / 256, 256, 0, stream>>>(Wih0, Whh0, Wih1, Whh1);

  // CSR build (exscan also re-zeroes cnt for use as fill cursor)
  exscan6_k<<<6, 256, 0, stream>>>();
  fill_all_k<<<dim3((100000 + 255) / 256, 6), 256, 0, stream>>>(R);

  // fused gather + GEMM per dst type
  gconv_gather_k<1><<<N_NODE_, 256, 0, stream>>>(
      x_pod, nullptr, nullptr, OI_OFF_IN, 0, 0, OI_CSR_IN, 0, 0,
      OF_OUTD_IN, 0, 0, OF_IND_IN, 0, 0,
      W_in, nullptr, nullptr, b_in, nullptr, nullptr, 1.0f, out_feat);
  gconv_gather_k<3><<<N_POD_, 256, 0, stream>>>(
      x_node, x_pod, x_svc, OI_OFF_NI, OI_OFF_II, OI_OFF_SI, OI_CSR_NI, OI_CSR_II, OI_CSR_SI,
      OF_OUTD_NI, OF_OUTD_II, OF_OUTD_SI, OF_IND_NI, OF_IND_II, OF_IND_SI,
      W_ni, W_ii, W_si, b_ni, b_ii, b_si, 1.0f / 3.0f,
      out_feat + (size_t)N_NODE_ * (T_ * H_));
  gconv_gather_k<2><<<N_SVC_, 256, 0, stream>>>(
      x_svc, x_pod, nullptr, OI_OFF_SC, OI_OFF_IS, 0, OI_CSR_SC, OI_CSR_IS, 0,
      OF_OUTD_SC, OF_OUTD_IS, 0, OF_IND_SC, OF_IND_IS, 0,
      W_sc, W_is, nullptr, b_sc, b_is, nullptr, 0.5f,
      out_feat + (size_t)(N_NODE_ + N_POD_) * (T_ * H_));

  // 2-layer LSTM: block-shared W stream via LDS, round-3 geometry
  lstm_wlds_k<<<512, 256, 0, stream>>>(
      out_feat, bih0, bhh0, bih1, bhh1, out_h);
}